// Round 2
// baseline (530.874 us; speedup 1.0000x reference)
//
#include <hip/hip_runtime.h>
#include <hip/hip_cooperative_groups.h>

namespace cg = cooperative_groups;

// DynamicRouting (CapsNet) on MI355X.
// B=16, I=32, C=8, J=10, D=16, H=W=6 -> DHW=576. num_routing=3 (fixed).
//
// Factorization: c[i,j] broadcasts over C and v doesn't depend on (i,c), so
// precompute U[b,i,j,dhw] = sum_c u_hat[b,i,c,j,dhw] (11.8 MB, L2-resident)
// and run all routing math on U. u_hat (94.4 MB) is read from HBM exactly once.
//
// R1->R2: fused all 3 routing iterations into ONE cooperative kernel
// (360 blocks x 256 = one thread per s element), grid.sync() between phases.
// 8 graph nodes -> 3 (memset, reduce_c, routing).

#define NB   16
#define NI   32
#define NC   8
#define NJ   10
#define ND   16
#define NHW  36
#define NDHW 576
#define NJDHW (NJ * NDHW)          // 5760
#define NTOT  (NB * NJ * NDHW)     // 92160
#define EPSV 1e-7f
#define GRID 360                   // 360*256 == NTOT exactly
#define TPB  256

// ---------------------------------------------------------------------------
// Kernel 1: U[b,i,j,dhw] = sum_c u_hat[b,i,c,j,dhw]   (float4-vectorized)
// ---------------------------------------------------------------------------
__global__ __launch_bounds__(256) void reduce_c_kernel(
    const float4* __restrict__ uh, float4* __restrict__ U)
{
    int t = blockIdx.x * 256 + threadIdx.x;     // < 16*32*10*144 = 737280
    int f4 = t % 144;
    int j  = (t / 144) % NJ;
    int bi = t / (144 * NJ);                    // b*NI + i
    const float4* p = uh + ((size_t)bi * NC) * (NJ * 144) + j * 144 + f4;
    float4 acc = make_float4(0.f, 0.f, 0.f, 0.f);
    #pragma unroll
    for (int c = 0; c < NC; ++c) {
        float4 v = p[(size_t)c * (NJ * 144)];
        acc.x += v.x; acc.y += v.y; acc.z += v.z; acc.w += v.w;
    }
    U[t] = acc;
}

// ---------------------------------------------------------------------------
// Kernel 2 (cooperative): all 3 routing iterations.
//   phase A: c = softmax(b_ij) per block (LDS);
//            s[e] = bias + sum_i c[i,j]*U[b,i,j,dhw]; n1[b] += |s| (segmented
//            block reduce -> <=2 global double atomics per block)
//   grid.sync
//   phase B (r<2): agreement[i,j] = sum_{b,dhw} U * scale[b]*s -> b_ij update
//   phase B (r=2): v output
// ---------------------------------------------------------------------------
__global__ __launch_bounds__(TPB) void routing_kernel(
    const float* __restrict__ U, const float* __restrict__ bias,
    float* __restrict__ s, float* __restrict__ bij,
    double* __restrict__ n1, float* __restrict__ out)
{
    cg::grid_group grid = cg::this_grid();
    const int tid = threadIdx.x;
    const int blk = blockIdx.x;
    const int e   = blk * TPB + tid;            // < NTOT, exact

    __shared__ float  c_sh[NI * NJ];
    __shared__ double red[8];
    __shared__ double sc_sh[NB];

    // element decomposition (constant across iterations)
    const int b   = e / NJDHW;
    const int rem = e - b * NJDHW;
    const int j   = rem / NDHW;
    const int dhw = rem - j * NDHW;
    const float bias_v = bias[j * ND + dhw / NHW];
    const float* Up = U + (((size_t)b * NI) * NJ + j) * NDHW + dhw;
    // segmented-reduce keys for this block
    const int b0 = (blk * TPB) / NJDHW;
    const int b1 = (blk * TPB + TPB - 1) / NJDHW;

    for (int r = 0; r < 3; ++r) {
        double* n1r = n1 + r * NB;

        // ---- coupling coefficients: softmax over j of b_ij rows ----
        if (tid < NI) {
            float row[NJ], m = -1e30f;
            #pragma unroll
            for (int jj = 0; jj < NJ; ++jj) {
                row[jj] = bij[tid * NJ + jj];
                m = fmaxf(m, row[jj]);
            }
            float ex[NJ], sum = 0.f;
            #pragma unroll
            for (int jj = 0; jj < NJ; ++jj) { ex[jj] = expf(row[jj] - m); sum += ex[jj]; }
            float inv = 1.f / sum;
            #pragma unroll
            for (int jj = 0; jj < NJ; ++jj) c_sh[tid * NJ + jj] = ex[jj] * inv;
        }
        __syncthreads();

        // ---- s ----
        float sv = bias_v;
        #pragma unroll
        for (int i = 0; i < NI; ++i)
            sv += c_sh[i * NJ + j] * Up[(size_t)i * NJ * NDHW];
        s[e] = sv;

        // ---- n1[b] += |s|, segmented by b (<=2 distinct b per block) ----
        {
            double a  = (double)fabsf(sv);
            double v0 = (b == b0) ? a : 0.0;
            double v1 = (b1 != b0 && b == b1) ? a : 0.0;
            #pragma unroll
            for (int off = 32; off > 0; off >>= 1) {
                v0 += __shfl_down(v0, off);
                v1 += __shfl_down(v1, off);
            }
            if ((tid & 63) == 0) { red[tid >> 6] = v0; red[4 + (tid >> 6)] = v1; }
            __syncthreads();
            if (tid == 0) {
                atomicAdd(&n1r[b0], red[0] + red[1] + red[2] + red[3]);
                if (b1 != b0)
                    atomicAdd(&n1r[b1], red[4] + red[5] + red[6] + red[7]);
            }
            __syncthreads();   // red[] reused next phase/iteration
        }

        __threadfence();
        grid.sync();           // n1 complete everywhere

        if (r < 2) {
            // ---- agreement + b_ij update: one (i,j) task per block ----
            if (tid < NB) {
                double n1v = n1r[tid];
                double nsq = n1v * n1v;
                sc_sh[tid] = (nsq / (1.0 + nsq)) / (n1v + (double)EPSV);
            }
            __syncthreads();
            if (blk < NI * NJ) {
                int ti = blk / NJ, tj = blk - ti * NJ;
                double acc = 0.0;
                for (int t = tid; t < NB * NDHW; t += TPB) {
                    int tb = t / NDHW, tdhw = t - tb * NDHW;
                    float Uv = U[(((size_t)(tb * NI + ti)) * NJ + tj) * NDHW + tdhw];
                    float svv = s[(size_t)tb * NJDHW + tj * NDHW + tdhw];
                    acc += (double)Uv * (double)svv * sc_sh[tb];
                }
                #pragma unroll
                for (int off = 32; off > 0; off >>= 1) acc += __shfl_down(acc, off);
                if ((tid & 63) == 0) red[tid >> 6] = acc;
                __syncthreads();
                if (tid == 0)
                    bij[blk] += (float)(red[0] + red[1] + red[2] + red[3]);
            }
            __threadfence();
            grid.sync();       // b_ij stable for next iteration's softmax
        } else {
            // ---- final output: v = (n1^2/(1+n1^2)) * (s/(n1+eps)) ----
            float n1f = (float)n1r[b];
            float nsq = n1f * n1f;
            out[e] = (nsq / (1.f + nsq)) * (sv / (n1f + EPSV));
        }
    }
}

extern "C" void kernel_launch(void* const* d_in, const int* in_sizes, int n_in,
                              void* d_out, int out_size, void* d_ws, size_t ws_size,
                              hipStream_t stream)
{
    const float* u_hat = (const float*)d_in[0];
    const float* bias  = (const float*)d_in[1];
    // d_in[2] = num_routing, fixed at 3 by the problem.

    float*  U   = (float*)d_ws;                         // 2,949,120 floats
    float*  s   = U + (size_t)NB * NI * NJ * NDHW;      //    92,160 floats
    float*  bij = s + NTOT;                             //       320 floats
    double* n1  = (double*)(bij + NI * NJ);             // 3*16 doubles (8B aligned)
    float*  out = (float*)d_out;

    // zero b_ij + all 3 n1 slices (ws is poisoned 0xAA before every launch)
    hipMemsetAsync(bij, 0, NI * NJ * sizeof(float) + 3 * NB * sizeof(double), stream);

    reduce_c_kernel<<<(NB * NI * NJ * 144) / 256, 256, 0, stream>>>(
        (const float4*)u_hat, (float4*)U);

    void* args[] = {(void*)&U, (void*)&bias, (void*)&s, (void*)&bij,
                    (void*)&n1, (void*)&out};
    hipLaunchCooperativeKernel((void*)routing_kernel, dim3(GRID), dim3(TPB),
                               args, 0, stream);
}

// Round 3
// 179.040 us; speedup vs baseline: 2.9651x; 2.9651x over previous
//
#include <hip/hip_runtime.h>

// DynamicRouting (CapsNet) on MI355X — 4-node version.
// B=16, I=32, C=8, J=10, D=16, H=W=6 -> DHW=576. num_routing=3 (fixed).
//
// Algebra: c[i,j] broadcasts over C and v is (i,c)-independent, so
//   U[b,i,j,:] = sum_c u_hat[b,i,c,j,:]          (11.8 MB, one HBM pass)
//   s_r        = sum_i c_r[i,j] U + bias
//   agreement_r[i,j] = sum_b sc_r[b] * G_r[b,i,j],  G_r = sum_dhw U*s_r
// G_r does NOT depend on n1 -> each kernel emits (s, n1-partials, G-partials)
// and the NEXT kernel's prologue redundantly (per block, ~43KB L2 reads)
// folds them into sc -> agreement -> b_ij -> softmax -> c[:,j].
// Iteration 0 has b_ij=0 -> c = 0.1 exactly, so the u_hat pass IS iteration 0.
// No atomics, no memsets, no stored b_ij. 4 kernels total.

#define NB   16
#define NI   32
#define NC   8
#define NJ   10
#define ND   16
#define NHW  36
#define NDHW 576
#define NJDHW (NJ * NDHW)          // 5760
#define NTOT  (NB * NJ * NDHW)     // 92160
#define EPSV 1e-7f
#define TPB  576                   // 9 waves; one thread per dhw

// u_hat strides: b:1474560  i:46080  c:5760  j:576
// U2 layout [b][j][i][dhw]: b:184320  j:18432  i:576

static __device__ __forceinline__ double wave_sum(double v) {
    #pragma unroll
    for (int off = 32; off > 0; off >>= 1) v += __shfl_down(v, off);
    return v;
}

// block-reduce |sv| over 576 threads -> n1p slot (thread 0 writes)
static __device__ __forceinline__ void n1_reduce(float sv, double* slot,
                                                 double* nred /*[9]*/) {
    int tid = threadIdx.x;
    double a = wave_sum((double)fabsf(sv));
    if ((tid & 63) == 0) nred[tid >> 6] = a;
    __syncthreads();
    if (tid == 0) {
        double t = nred[0];
        #pragma unroll
        for (int w = 1; w < 9; ++w) t += nred[w];
        *slot = t;
    }
}

// block-reduce Uv[i]*sv over 576 threads for all 32 i -> Gp[...+i]
static __device__ __forceinline__ void g_reduce(const float* Uv, float sv,
                                                double* gslot,
                                                double (*gred)[32] /*[9][32]*/) {
    int tid = threadIdx.x, w = tid >> 6, lane = tid & 63;
    #pragma unroll
    for (int i = 0; i < NI; ++i) {
        double p = wave_sum((double)Uv[i] * (double)sv);
        if (lane == 0) gred[w][i] = p;
    }
    __syncthreads();
    if (tid < NI) {
        double t = gred[0][tid];
        #pragma unroll
        for (int w2 = 1; w2 < 9; ++w2) t += gred[w2][tid];
        gslot[tid] = t;
    }
}

// ---------------------------------------------------------------------------
// Kernel A1 = channel-reduce + routing iteration 0 (c == 0.1 exactly).
// One block per (b,j), 576 threads (= dhw). Writes U2, n1p[0], Gp[0].
// ---------------------------------------------------------------------------
__global__ __launch_bounds__(TPB) void a1_kernel(
    const float* __restrict__ uh, const float* __restrict__ bias,
    float* __restrict__ U2, double* __restrict__ n1p, double* __restrict__ Gp)
{
    __shared__ double nred[9];
    __shared__ double gred[9][32];

    const int blk = blockIdx.x;            // b*NJ + j
    const int b = blk / NJ, j = blk - b * NJ;
    const int tid = threadIdx.x;           // dhw
    const float cw = 1.0f / 10.0f;         // softmax(0) row

    const float* ub = uh + (size_t)b * 1474560 + j * 576 + tid;
    float* u2b = U2 + (size_t)b * 184320 + j * 18432 + tid;

    float Uv[NI];
    float sv = bias[j * ND + tid / NHW];
    #pragma unroll 4
    for (int i = 0; i < NI; ++i) {
        float acc = 0.f;
        #pragma unroll
        for (int c = 0; c < NC; ++c)
            acc += ub[(size_t)i * 46080 + c * 5760];
        Uv[i] = acc;
        u2b[i * 576] = acc;
        sv += cw * acc;
    }

    n1_reduce(sv, &n1p[b * NJ + j], nred);
    g_reduce(Uv, sv, &Gp[(size_t)(b * NJ + j) * NI], gred);
}

// ---------------------------------------------------------------------------
// Kernel AB<R> = routing iteration R (R=1,2). Prologue redundantly rebuilds
// b_ij from n1p/Gp of iterations 0..R-1, softmaxes, then does the s pass.
// R=1: emits n1p[1], Gp[1].  R=2: emits n1p[2] and s (for the V kernel).
// ---------------------------------------------------------------------------
template <int R>
__global__ __launch_bounds__(TPB) void ab_kernel(
    const float* __restrict__ U2, const float* __restrict__ bias,
    const double* __restrict__ n1p, double* __restrict__ Gp,
    double* __restrict__ n1p_out, double* __restrict__ Gp_out,
    float* __restrict__ s)
{
    __shared__ double sc_sh[2][NB];
    __shared__ float  bij_sh[NI * NJ];
    __shared__ float  c_sh[NI];
    __shared__ double nred[9];
    __shared__ double gred[9][32];

    const int blk = blockIdx.x;            // b*NJ + j
    const int b = blk / NJ, j = blk - b * NJ;
    const int tid = threadIdx.x;           // dhw

    // ---- prologue: sc for each prior iteration ----
    if (tid < R * NB) {
        int rr = tid / NB, bb = tid - rr * NB;
        double n1 = 0.0;
        #pragma unroll
        for (int jj = 0; jj < NJ; ++jj) n1 += n1p[rr * (NB * NJ) + bb * NJ + jj];
        double nsq = n1 * n1;
        sc_sh[rr][bb] = (nsq / (1.0 + nsq)) / (n1 + (double)EPSV);
    }
    __syncthreads();

    // ---- b_ij[i,jj] = sum_rr sum_b sc*G ----
    if (tid < NI * NJ) {
        int i = tid / NJ, jj = tid - i * NJ;
        double a = 0.0;
        #pragma unroll
        for (int rr = 0; rr < R; ++rr)
            #pragma unroll
            for (int bb = 0; bb < NB; ++bb)
                a += sc_sh[rr][bb] *
                     Gp[(size_t)(rr * NB + bb) * NJ * NI + (size_t)jj * NI + i];
        bij_sh[tid] = (float)a;
    }
    __syncthreads();

    // ---- softmax rows -> c[:, j] ----
    if (tid < NI) {
        float m = -1e30f;
        #pragma unroll
        for (int jj = 0; jj < NJ; ++jj) m = fmaxf(m, bij_sh[tid * NJ + jj]);
        float sum = 0.f;
        #pragma unroll
        for (int jj = 0; jj < NJ; ++jj) sum += expf(bij_sh[tid * NJ + jj] - m);
        c_sh[tid] = expf(bij_sh[tid * NJ + j] - m) / sum;
    }
    __syncthreads();

    // ---- s pass ----
    const float* u2b = U2 + (size_t)b * 184320 + j * 18432 + tid;
    float Uv[NI];
    float sv = bias[j * ND + tid / NHW];
    #pragma unroll
    for (int i = 0; i < NI; ++i) {
        Uv[i] = u2b[i * 576];
        sv += c_sh[i] * Uv[i];
    }

    if (R == 2) s[(size_t)blk * NDHW + tid] = sv;

    n1_reduce(sv, &n1p_out[b * NJ + j], nred);
    if (R == 1)
        g_reduce(Uv, sv, &Gp_out[(size_t)(b * NJ + j) * NI], gred);
}

// ---------------------------------------------------------------------------
// Kernel V: v = (n1^2/(1+n1^2)) * (s/(n1+eps)).  b is wave-uniform (5760%64==0).
// ---------------------------------------------------------------------------
__global__ __launch_bounds__(256) void v_kernel(
    const float* __restrict__ s, const double* __restrict__ n1p2,
    float* __restrict__ out)
{
    int e = blockIdx.x * 256 + threadIdx.x;    // < NTOT exact
    int b = e / NJDHW;
    double n1 = 0.0;
    #pragma unroll
    for (int jj = 0; jj < NJ; ++jj) n1 += n1p2[b * NJ + jj];
    float n1f = (float)n1;
    float nsq = n1f * n1f;
    out[e] = (nsq / (1.f + nsq)) * (s[e] / (n1f + EPSV));
}

extern "C" void kernel_launch(void* const* d_in, const int* in_sizes, int n_in,
                              void* d_out, int out_size, void* d_ws, size_t ws_size,
                              hipStream_t stream)
{
    const float* u_hat = (const float*)d_in[0];
    const float* bias  = (const float*)d_in[1];
    // d_in[2] = num_routing, fixed at 3 by the problem.

    float*  U2  = (float*)d_ws;                          // 2,949,120 f
    float*  s   = U2 + (size_t)NB * NJ * NI * NDHW;      //    92,160 f
    double* n1p = (double*)(s + NTOT);                   // 3*160 d (8B aligned)
    double* Gp  = n1p + 3 * NB * NJ;                     // 2*5120 d
    float*  out = (float*)d_out;

    a1_kernel<<<NB * NJ, TPB, 0, stream>>>(u_hat, bias, U2, n1p, Gp);
    ab_kernel<1><<<NB * NJ, TPB, 0, stream>>>(
        U2, bias, n1p, Gp, n1p + NB * NJ, Gp + NB * NJ * NI, s);
    ab_kernel<2><<<NB * NJ, TPB, 0, stream>>>(
        U2, bias, n1p, Gp, n1p + 2 * NB * NJ, nullptr, s);
    v_kernel<<<NTOT / 256, 256, 0, stream>>>(s, n1p + 2 * NB * NJ, out);
}

// Round 5
// 178.009 us; speedup vs baseline: 2.9823x; 1.0058x over previous
//
#include <hip/hip_runtime.h>

// DynamicRouting (CapsNet) on MI355X — 4-node version (R3 structure, validated
// through the post-timing tripwire) with a vectorized u_hat pass.
// B=16, I=32, C=8, J=10, D=16, H=W=6 -> DHW=576. num_routing=3 (fixed).
//
// Algebra: c[i,j] broadcasts over C and v is (i,c)-independent, so
//   U[b,i,j,:] = sum_c u_hat[b,i,c,j,:]          (11.8 MB, one HBM pass)
//   s_r        = sum_i c_r[i,j] U + bias
//   agreement_r[i,j] = sum_b sc_r[b] * G_r[b,i,j],  G_r = sum_dhw U*s_r
// Each iteration kernel emits (n1-partials, G-partials); the NEXT kernel's
// prologue redundantly (per block, ~43KB L2 reads) folds them into
// sc -> agreement -> b_ij -> softmax -> c[:,j]. Iteration 0 has b_ij=0 ->
// c = 0.1 exactly. No atomics, no memsets, no stored b_ij.
//
// R4 post-mortem: splitting the u_hat pass into a standalone writer kernel
// made the timed-graph output stably diverge (~1e-4, consistent with stale
// U2 lines read as ~0 poison). R3's fused producer structure passed the
// tripwire twice -> revert to it. R3's perf bug was SCALAR u_hat loads;
// R5 fixes that inside a1: phase 1 channel-reduces with float4 loads
// (8/thread) into a 72 KiB LDS tile + coalesced float4 U2 stores; phase 2
// is R3's bit-identical iteration-0 math reading scalars from LDS.

#define NB   16
#define NI   32
#define NC   8
#define NJ   10
#define ND   16
#define NHW  36
#define NDHW 576
#define NJDHW (NJ * NDHW)          // 5760
#define NTOT  (NB * NJ * NDHW)     // 92160
#define EPSV 1e-7f
#define TPB  576                   // 9 waves; one thread per dhw

// U2 layout [b][j][i][dhw]: strides (floats) b:184320  j:18432  i:576

static __device__ __forceinline__ double wave_sum(double v) {
    #pragma unroll
    for (int off = 32; off > 0; off >>= 1) v += __shfl_down(v, off);
    return v;
}

// block-reduce |sv| over 576 threads -> n1p slot (thread 0 writes)
static __device__ __forceinline__ void n1_reduce(float sv, double* slot,
                                                 double* nred /*[9]*/) {
    int tid = threadIdx.x;
    double a = wave_sum((double)fabsf(sv));
    if ((tid & 63) == 0) nred[tid >> 6] = a;
    __syncthreads();
    if (tid == 0) {
        double t = nred[0];
        #pragma unroll
        for (int w = 1; w < 9; ++w) t += nred[w];
        *slot = t;
    }
}

// block-reduce Uv[i]*sv over 576 threads for all 32 i -> gslot[i]
static __device__ __forceinline__ void g_reduce(const float* Uv, float sv,
                                                double* gslot,
                                                double (*gred)[32] /*[9][32]*/) {
    int tid = threadIdx.x, w = tid >> 6, lane = tid & 63;
    #pragma unroll
    for (int i = 0; i < NI; ++i) {
        double p = wave_sum((double)Uv[i] * (double)sv);
        if (lane == 0) gred[w][i] = p;
    }
    __syncthreads();
    if (tid < NI) {
        double t = gred[0][tid];
        #pragma unroll
        for (int w2 = 1; w2 < 9; ++w2) t += gred[w2][tid];
        gslot[tid] = t;
    }
}

// ---------------------------------------------------------------------------
// Kernel A1 = channel-reduce (float4) + routing iteration 0 (c == 0.1).
// One block per (b,j), 576 threads.
// Phase 1: 8 float4/thread cover the 32x144 (i,f4) tile; sum over c=0..7;
//          store to LDS tile AND to global U2 (coalesced float4, linear).
// Phase 2: R3's iteration-0 body, Uv[i] read from LDS (conflict-free).
// ---------------------------------------------------------------------------
__global__ __launch_bounds__(TPB) void a1_kernel(
    const float4* __restrict__ uh4, const float* __restrict__ bias,
    float4* __restrict__ U2f4, double* __restrict__ n1p, double* __restrict__ Gp)
{
    __shared__ float4  Utile4[NI * 144];   // 72 KiB: [i][f4] for this (b,j)
    __shared__ double  nred[9];
    __shared__ double  gred[9][32];

    const int blk = blockIdx.x;            // b*NJ + j
    const int b = blk / NJ, j = blk - b * NJ;
    const int tid = threadIdx.x;           // dhw in phase 2

    // ---- phase 1: U[b,:,j,:] = sum_c u_hat, vectorized ----
    // u_hat float4 index: ((b*NI+i)*NC + c)*1440 + j*144 + f4
    #pragma unroll
    for (int g = 0; g < 8; ++g) {
        int lin = g * TPB + tid;           // < 4608 = 32*144
        int i  = lin / 144, f4 = lin - i * 144;
        const float4* p = uh4 + ((size_t)(b * NI + i) * NC) * 1440 + j * 144 + f4;
        float4 acc = make_float4(0.f, 0.f, 0.f, 0.f);
        #pragma unroll
        for (int c = 0; c < NC; ++c) {
            float4 v = p[(size_t)c * 1440];
            acc.x += v.x; acc.y += v.y; acc.z += v.z; acc.w += v.w;
        }
        Utile4[lin] = acc;
        U2f4[(size_t)blk * 4608 + lin] = acc;   // U2[b][j][i][dhw], linear
    }
    __syncthreads();

    // ---- phase 2: iteration 0 (c = 0.1 exactly) ----
    const float* Utile = (const float*)Utile4;
    const float cw = 1.0f / 10.0f;
    float Uv[NI];
    float sv = bias[j * ND + tid / NHW];
    #pragma unroll
    for (int i = 0; i < NI; ++i) {
        Uv[i] = Utile[i * NDHW + tid];
        sv += cw * Uv[i];
    }

    n1_reduce(sv, &n1p[blk], nred);
    g_reduce(Uv, sv, &Gp[(size_t)blk * NI], gred);
}

// ---------------------------------------------------------------------------
// Kernel AB<R> = routing iteration R (R=1,2). Prologue redundantly rebuilds
// b_ij from n1p/Gp of iterations 0..R-1, softmaxes, then does the s pass.
// R=1: emits n1p[1], Gp[1].  R=2: emits n1p[2] and s (for the V kernel).
// ---------------------------------------------------------------------------
template <int R>
__global__ __launch_bounds__(TPB) void ab_kernel(
    const float* __restrict__ U2, const float* __restrict__ bias,
    const double* __restrict__ n1p, double* __restrict__ Gp,
    double* __restrict__ n1p_out, double* __restrict__ Gp_out,
    float* __restrict__ s)
{
    __shared__ double sc_sh[2][NB];
    __shared__ float  bij_sh[NI * NJ];
    __shared__ float  c_sh[NI];
    __shared__ double nred[9];
    __shared__ double gred[9][32];

    const int blk = blockIdx.x;            // b*NJ + j
    const int b = blk / NJ, j = blk - b * NJ;
    const int tid = threadIdx.x;           // dhw

    // ---- prologue: sc for each prior iteration ----
    if (tid < R * NB) {
        int rr = tid / NB, bb = tid - rr * NB;
        double n1 = 0.0;
        #pragma unroll
        for (int jj = 0; jj < NJ; ++jj) n1 += n1p[rr * (NB * NJ) + bb * NJ + jj];
        double nsq = n1 * n1;
        sc_sh[rr][bb] = (nsq / (1.0 + nsq)) / (n1 + (double)EPSV);
    }
    __syncthreads();

    // ---- b_ij[i,jj] = sum_rr sum_b sc*G ----
    if (tid < NI * NJ) {
        int i = tid / NJ, jj = tid - i * NJ;
        double a = 0.0;
        #pragma unroll
        for (int rr = 0; rr < R; ++rr)
            #pragma unroll
            for (int bb = 0; bb < NB; ++bb)
                a += sc_sh[rr][bb] *
                     Gp[(size_t)(rr * NB + bb) * NJ * NI + (size_t)jj * NI + i];
        bij_sh[tid] = (float)a;
    }
    __syncthreads();

    // ---- softmax rows -> c[:, j] ----
    if (tid < NI) {
        float m = -1e30f;
        #pragma unroll
        for (int jj = 0; jj < NJ; ++jj) m = fmaxf(m, bij_sh[tid * NJ + jj]);
        float sum = 0.f;
        #pragma unroll
        for (int jj = 0; jj < NJ; ++jj) sum += expf(bij_sh[tid * NJ + jj] - m);
        c_sh[tid] = expf(bij_sh[tid * NJ + j] - m) / sum;
    }
    __syncthreads();

    // ---- s pass ----
    const float* u2b = U2 + (size_t)b * 184320 + j * 18432 + tid;
    float Uv[NI];
    float sv = bias[j * ND + tid / NHW];
    #pragma unroll
    for (int i = 0; i < NI; ++i) {
        Uv[i] = u2b[i * 576];
        sv += c_sh[i] * Uv[i];
    }

    if (R == 2) s[(size_t)blk * NDHW + tid] = sv;

    n1_reduce(sv, &n1p_out[b * NJ + j], nred);
    if (R == 1)
        g_reduce(Uv, sv, &Gp_out[(size_t)(b * NJ + j) * NI], gred);
}

// ---------------------------------------------------------------------------
// Kernel V: v = (n1^2/(1+n1^2)) * (s/(n1+eps)).  b is wave-uniform (5760%64==0).
// ---------------------------------------------------------------------------
__global__ __launch_bounds__(256) void v_kernel(
    const float* __restrict__ s, const double* __restrict__ n1p2,
    float* __restrict__ out)
{
    int e = blockIdx.x * 256 + threadIdx.x;    // < NTOT exact
    int b = e / NJDHW;
    double n1 = 0.0;
    #pragma unroll
    for (int jj = 0; jj < NJ; ++jj) n1 += n1p2[b * NJ + jj];
    float n1f = (float)n1;
    float nsq = n1f * n1f;
    out[e] = (nsq / (1.f + nsq)) * (s[e] / (n1f + EPSV));
}

extern "C" void kernel_launch(void* const* d_in, const int* in_sizes, int n_in,
                              void* d_out, int out_size, void* d_ws, size_t ws_size,
                              hipStream_t stream)
{
    const float* u_hat = (const float*)d_in[0];
    const float* bias  = (const float*)d_in[1];
    // d_in[2] = num_routing, fixed at 3 by the problem.

    float*  U2  = (float*)d_ws;                          // 2,949,120 f
    float*  s   = U2 + (size_t)NB * NJ * NI * NDHW;      //    92,160 f
    double* n1p = (double*)(s + NTOT);                   // 3*160 d (8B aligned)
    double* Gp  = n1p + 3 * NB * NJ;                     // 2*5120 d
    float*  out = (float*)d_out;

    a1_kernel<<<NB * NJ, TPB, 0, stream>>>(
        (const float4*)u_hat, bias, (float4*)U2, n1p, Gp);
    ab_kernel<1><<<NB * NJ, TPB, 0, stream>>>(
        U2, bias, n1p, Gp, n1p + NB * NJ, Gp + NB * NJ * NI, s);
    ab_kernel<2><<<NB * NJ, TPB, 0, stream>>>(
        U2, bias, n1p, Gp, n1p + 2 * NB * NJ, nullptr, s);
    v_kernel<<<NTOT / 256, 256, 0, stream>>>(s, n1p + 2 * NB * NJ, out);
}